// Round 3
// baseline (39.224 us; speedup 1.0000x reference)
//
#include <hip/hip_runtime.h>

typedef __attribute__((ext_vector_type(4))) float f32x4;

#define N_MOLS   2000
#define NATOM    64
#define PPM      (NATOM * (NATOM - 1))   // 4032 pairs per molecule
#define NPAIRS   (N_MOLS * PPM)          // 8,064,000
#define NGROUPS  (NPAIRS / 4)            // 2,016,000 = 7875 blocks * 256 threads exactly

__global__ __launch_bounds__(256) void nl_pairs_kernel(const float* __restrict__ pos,
                                                       float* __restrict__ out) {
    // A block covers 1024 consecutive pairs -> at most 2 molecules (1536 B of positions).
    __shared__ float smem[2 * NATOM * 3];            // 384 floats

    const int tid    = threadIdx.x;
    const int gblk   = blockIdx.x * 256;             // first group of this block
    const int k0_blk = gblk * 4;                     // first pair of this block
    const int mol0   = k0_blk / PPM;                 // first molecule touched

    // stage molecules [mol0, mol0+1] (clamped) with coalesced float4 loads
    const int nvec = (mol0 >= N_MOLS - 1) ? 48 : 96; // float4 count (192 floats per molecule)
    if (tid < nvec) {
        reinterpret_cast<f32x4*>(smem)[tid] =
            reinterpret_cast<const f32x4*>(pos + (long)mol0 * (NATOM * 3))[tid];
    }
    __syncthreads();

    const int g  = gblk + tid;                       // grid is exact: no bounds check
    const int k0 = g * 4;
    const int mol = k0 / PPM;
    int       kl  = k0 - mol * PPM;
    const int base = mol * NATOM;
    int i = kl / 63;                                 // local i row
    int t = kl - i * 63;                             // slot within row (j skips i)

    const float* mp = smem + (mol - mol0) * (NATOM * 3);
    float pix = mp[i*3+0], piy = mp[i*3+1], piz = mp[i*3+2];

    f32x4 vi, vj, vd;
    float rr[12];

    #pragma unroll
    for (int u = 0; u < 4; ++u) {
        const int j = (t < i) ? t : (t + 1);
        const float pjx = mp[j*3+0], pjy = mp[j*3+1], pjz = mp[j*3+2];

        // strict IEEE f32, no FMA contraction -> bit-exact vs numpy:
        // d = sqrt((dx*dx + dy*dy) + dz*dz)
        const float dx = __fsub_rn(pjx, pix);
        const float dy = __fsub_rn(pjy, piy);
        const float dz = __fsub_rn(pjz, piz);
        const float d2 = __fadd_rn(__fadd_rn(__fmul_rn(dx, dx), __fmul_rn(dy, dy)),
                                   __fmul_rn(dz, dz));
        const float d  = __fsqrt_rn(d2);
        const bool  in = (d <= 5.0f);

        vi[u] = (float)(base + i);                   // exact: < 2^24
        vj[u] = (float)(base + j);
        vd[u] = in ? d : 0.0f;
        rr[3*u+0] = in ? dx : 0.0f;
        rr[3*u+1] = in ? dy : 0.0f;
        rr[3*u+2] = in ? dz : 0.0f;

        if (u < 3) {                                 // advance (i,t) within the molecule
            ++t;
            if (t == 63) { t = 0; ++i; pix = mp[i*3+0]; piy = mp[i*3+1]; piz = mp[i*3+2]; }
        }
    }

    // layout: [i row | j row | d_ij | r_ij], all float32, all stores 16B-aligned
    *reinterpret_cast<f32x4*>(out + k0)            = vi;
    *reinterpret_cast<f32x4*>(out + NPAIRS + k0)   = vj;
    *reinterpret_cast<f32x4*>(out + 2*NPAIRS + k0) = vd;
    float* rb = out + (long)3 * NPAIRS + (long)3 * k0;   // 3*k0 % 4 == 0
    *reinterpret_cast<f32x4*>(rb + 0) = f32x4{rr[0], rr[1], rr[2],  rr[3]};
    *reinterpret_cast<f32x4*>(rb + 4) = f32x4{rr[4], rr[5], rr[6],  rr[7]};
    *reinterpret_cast<f32x4*>(rb + 8) = f32x4{rr[8], rr[9], rr[10], rr[11]};
}

extern "C" void kernel_launch(void* const* d_in, const int* in_sizes, int n_in,
                              void* d_out, int out_size, void* d_ws, size_t ws_size,
                              hipStream_t stream) {
    const float* pos = (const float*)d_in[0];
    float* out = (float*)d_out;
    const int blocks = NGROUPS / 256;                // 7875, exact
    nl_pairs_kernel<<<blocks, 256, 0, stream>>>(pos, out);
}

// Round 4
// 35.473 us; speedup vs baseline: 1.1057x; 1.1057x over previous
//
#include <hip/hip_runtime.h>

typedef __attribute__((ext_vector_type(4))) float f32x4;

#define N_MOLS   2000
#define NATOM    64
#define PPM      (NATOM * (NATOM - 1))   // 4032 pairs per molecule
#define NPAIRS   (N_MOLS * PPM)          // 8,064,000
#define NGROUPS  (NPAIRS / 4)            // 2,016,000 = 7875 blocks * 256 threads exactly

__global__ __launch_bounds__(256) void nl_pairs_kernel(const float* __restrict__ pos,
                                                       float* __restrict__ out) {
    // A block covers 1024 consecutive pairs -> at most 2 molecules (1536 B of positions).
    __shared__ float sPos[2 * NATOM * 3];   // 384 floats
    __shared__ f32x4 sR[768];               // 12 KB: block's r_ij, staged for dense stores

    const int tid    = threadIdx.x;
    const int gblk   = blockIdx.x * 256;    // first group of this block
    const int k0_blk = gblk * 4;            // first pair of this block
    const int mol0   = k0_blk / PPM;        // first molecule touched

    // stage molecules [mol0, mol0+1] (clamped) with coalesced float4 loads
    const int nvec = (mol0 >= N_MOLS - 1) ? 48 : 96;
    if (tid < nvec) {
        reinterpret_cast<f32x4*>(sPos)[tid] =
            reinterpret_cast<const f32x4*>(pos + (long)mol0 * (NATOM * 3))[tid];
    }
    __syncthreads();

    const int k0  = (gblk + tid) * 4;       // this thread's first pair
    const int mol = k0 / PPM;
    int       kl  = k0 - mol * PPM;
    const int base = mol * NATOM;
    int i = kl / 63;                        // local i row
    int t = kl - i * 63;                    // slot within row (j skips i)

    const float* mp = sPos + (mol - mol0) * (NATOM * 3);
    float pix = mp[i*3+0], piy = mp[i*3+1], piz = mp[i*3+2];

    f32x4 vi, vj, vd;
    float rr[12];

    #pragma unroll
    for (int u = 0; u < 4; ++u) {
        const int j = (t < i) ? t : (t + 1);
        const float pjx = mp[j*3+0], pjy = mp[j*3+1], pjz = mp[j*3+2];

        // strict IEEE f32, no FMA contraction -> bit-exact vs numpy:
        // d = sqrt((dx*dx + dy*dy) + dz*dz)
        const float dx = __fsub_rn(pjx, pix);
        const float dy = __fsub_rn(pjy, piy);
        const float dz = __fsub_rn(pjz, piz);
        const float d2 = __fadd_rn(__fadd_rn(__fmul_rn(dx, dx), __fmul_rn(dy, dy)),
                                   __fmul_rn(dz, dz));
        const float d  = __fsqrt_rn(d2);
        const bool  in = (d <= 5.0f);

        vi[u] = (float)(base + i);          // exact: < 2^24
        vj[u] = (float)(base + j);
        vd[u] = in ? d : 0.0f;
        rr[3*u+0] = in ? dx : 0.0f;
        rr[3*u+1] = in ? dy : 0.0f;
        rr[3*u+2] = in ? dz : 0.0f;

        if (u < 3) {                        // advance (i,t) within the molecule
            ++t;
            if (t == 63) { t = 0; ++i; pix = mp[i*3+0]; piy = mp[i*3+1]; piz = mp[i*3+2]; }
        }
    }

    // i/j/d streams: dense 16B/lane stores straight from registers
    *reinterpret_cast<f32x4*>(out + k0)            = vi;
    *reinterpret_cast<f32x4*>(out + NPAIRS + k0)   = vj;
    *reinterpret_cast<f32x4*>(out + 2*NPAIRS + k0) = vd;

    // r stream: transpose through LDS so the global stores are fully dense.
    // Write pattern (48-B lane stride) is bank-conflict-free: lanes 0..7 cover
    // all 32 banks exactly once per phase.
    sR[3*tid + 0] = f32x4{rr[0], rr[1], rr[2],  rr[3]};
    sR[3*tid + 1] = f32x4{rr[4], rr[5], rr[6],  rr[7]};
    sR[3*tid + 2] = f32x4{rr[8], rr[9], rr[10], rr[11]};
    __syncthreads();

    // block's r region = 3072 floats = 768 f32x4, written dense (16B lane stride)
    f32x4* rv = reinterpret_cast<f32x4*>(out + (long)3 * NPAIRS + (long)3 * k0_blk);
    rv[tid]       = sR[tid];
    rv[tid + 256] = sR[tid + 256];
    rv[tid + 512] = sR[tid + 512];
}

extern "C" void kernel_launch(void* const* d_in, const int* in_sizes, int n_in,
                              void* d_out, int out_size, void* d_ws, size_t ws_size,
                              hipStream_t stream) {
    const float* pos = (const float*)d_in[0];
    float* out = (float*)d_out;
    const int blocks = NGROUPS / 256;       // 7875, exact
    nl_pairs_kernel<<<blocks, 256, 0, stream>>>(pos, out);
}